// Round 9
// baseline (614.489 us; speedup 1.0000x reference)
//
#include <hip/hip_runtime.h>
#include <hip/hip_bf16.h>
#include <stdint.h>

#define M_TOTAL 16384
#define N_TOTAL 4096
#define K_TOTAL 4096
#define NSTEP (K_TOTAL / 64)   // 64 K-steps of 64
#define NT32 (K_TOTAL / 32)

typedef __attribute__((ext_vector_type(8))) short bf16x8;
typedef __attribute__((ext_vector_type(4))) float f32x4;

__device__ __forceinline__ void gload_lds16(const void* g, void* l) {
    __builtin_amdgcn_global_load_lds(
        (const __attribute__((address_space(1))) uint32_t*)g,
        (__attribute__((address_space(3))) uint32_t*)l, 16, 0, 0);
}

// ---------------------------------------------------------------------------
// Kernel 0: X f32 -> bf16 (134 MB, L3-resident afterwards).
// ---------------------------------------------------------------------------
__global__ __launch_bounds__(256) void k_convX(const float* __restrict__ X,
                                               __hip_bfloat16* __restrict__ Xb) {
    size_t t = (size_t)blockIdx.x * 256 + threadIdx.x;
    const float* p = X + t * 8;
    float4 a = *(const float4*)p;
    float4 b = *(const float4*)(p + 4);
    __hip_bfloat162 o[4] = {
        __float22bfloat162_rn(make_float2(a.x, a.y)),
        __float22bfloat162_rn(make_float2(a.z, a.w)),
        __float22bfloat162_rn(make_float2(b.x, b.y)),
        __float22bfloat162_rn(make_float2(b.z, b.w))};
    *(int4*)(Xb + t * 8) = *(int4*)&o[0];
}

// ---------------------------------------------------------------------------
// Kernel 1: packed int4 -> bf16 W[N][K]. word j of row n: k=2j lo nibble,
// k=2j+1 hi nibble; codes 0..15 -> -8..7, scale[n][k/32] (f32).
// ---------------------------------------------------------------------------
__global__ __launch_bounds__(256) void k_dequant(const int* __restrict__ pw,
                                                 const float* __restrict__ sc,
                                                 __hip_bfloat16* __restrict__ W) {
    int t = blockIdx.x * 256 + threadIdx.x;
    int row = t >> 8;
    int w0 = (t & 255) << 3;
    const int* p = pw + (size_t)row * 2048 + w0;
    int4 q0 = *(const int4*)p;
    int4 q1 = *(const int4*)(p + 4);
    float s = sc[row * 128 + (w0 >> 4)];
    float ns8 = -8.0f * s;
    int w[8] = {q0.x, q0.y, q0.z, q0.w, q1.x, q1.y, q1.z, q1.w};
    __hip_bfloat162 o[8];
#pragma unroll
    for (int i = 0; i < 8; ++i) {
        float lo = fmaf((float)(w[i] & 15), s, ns8);
        float hi = fmaf((float)(w[i] >> 4), s, ns8);
        o[i] = __float22bfloat162_rn(make_float2(lo, hi));
    }
    __hip_bfloat16* dst = W + (size_t)row * 4096 + w0 * 2;
    *(int4*)dst = *(int4*)&o[0];
    *(int4*)(dst + 8) = *(int4*)&o[4];
}

// ---------------------------------------------------------------------------
// Kernel 2 (tier A): 8-phase, 256x256, BK=64, 2 dbuf, 8 waves (2Mx4N).
// ROUND 9 CHANGE: single barrier per phase (end-barriers removed) so phase
// p+1's ds_reads/stages issue while slower waves run phase p's MFMA ->
// LDS service overlaps MFMA pipe.
//
// Race rule: stage at phase p is issued after BAR(p-1) => all waves have
// completed MFMA(p-2) => all reads from phases <= p-2 are consumed. Every
// stage below targets a half-buffer whose last reads are >= 2 phases old:
//   p1: B(s+1)h1->b1  [b1-B read p5',p6' prev iter: gap 3]
//   p2: A(s+1)h0->b1  [b1-A read p5',p7': gap 3]
//   p3: A(s+1)h1->b1  [gap 4]
//   p4: B(s+2)h0->b0  [b0-B read p1,p2: gap 2]
//   p5: B(s+2)h1->b0  [gap 3]
//   p6: A(s+2)h0->b0  [b0-A read p1,p3: gap 3]
//   p7: A(s+2)h1->b0  [gap 4]
//   p8: B(s+3)h0->b1  [b1-B read p5,p6: gap 2]
// Publishes: after p4 MFMA: vmcnt(2) (drains p8',p1,p2,p3 = all of b1's
// K-step s+1 data; leaves p4) + BAR. After p8: vmcnt(2) (drains p4..p7 =
// b0's s+2 data; leaves p8) + BAR. Never vmcnt(0) except final iters.
//
// LDS layout (0-conflict, verified r6/r8): 16B slot = (row%64>>3)*64 +
// chunk*8 + row%8 per 64-row block; linear gload dest, permuted global src.
// ---------------------------------------------------------------------------
__global__ __launch_bounds__(512, 2) void k_gemm8(const __hip_bfloat16* __restrict__ Xb,
                                                  const __hip_bfloat16* __restrict__ Wb,
                                                  float* __restrict__ out) {
    __shared__ __align__(16) short L[2][2][2][8192];  // [buf][A/B][half][16KB]

    int bid = blockIdx.x;
    int swz = (bid & 7) * 128 + (bid >> 3);           // XCD-bijective (1024%8==0)
    int bn = swz & 15, bm = swz >> 4;
    int m0 = bm * 256, n0 = bn * 256;
    int t = threadIdx.x, lane = t & 63, wv = t >> 6;
    int wm = wv >> 2, wn = wv & 3, wnh = wn >> 1;

    // staging source: thread t -> row (t>>6)*8+(t&7) of 64-row block, chunk (t>>3)&7
    int srow = (t >> 6) * 8 + (t & 7);
    int scol = ((t >> 3) & 7) * 8;
    const __hip_bfloat16* gA = Xb + (size_t)(m0 + srow) * K_TOTAL + scol;
    const __hip_bfloat16* gB = Wb + (size_t)(n0 + srow) * K_TOTAL + scol;

    auto stA = [&](int b, int h, int s_) {
        gload_lds16(gA + (size_t)(h * 128) * K_TOTAL + s_ * 64, &L[b][0][h][t * 8]);
        gload_lds16(gA + (size_t)(h * 128 + 64) * K_TOTAL + s_ * 64, &L[b][0][h][4096 + t * 8]);
    };
    auto stB = [&](int b, int h, int s_) {
        gload_lds16(gB + (size_t)(h * 128) * K_TOTAL + s_ * 64, &L[b][1][h][t * 8]);
        gload_lds16(gB + (size_t)(h * 128 + 64) * K_TOTAL + s_ * 64, &L[b][1][h][4096 + t * 8]);
    };

    // frag-read lane offsets (shorts)
    const int lo0 = ((lane & 15) >> 3) * 512 + ((lane >> 4) * 8 + (lane & 7)) * 8;
    const int lo1 = lo0 + 256;
    const int cbase = (wn & 1) * 4096;

    f32x4 acc[8][4];
#pragma unroll
    for (int f = 0; f < 8; ++f)
#pragma unroll
        for (int j = 0; j < 4; ++j) acc[f][j] = (f32x4)(0.0f);

    bf16x8 Af[8], Bq01[4], Bq23[4];

#define RD_A(rfb) { _Pragma("unroll") for (int rf = 0; rf < 4; ++rf) { \
        const int rb = (((rfb) + rf) >> 2) * 4096 + (((rfb) + rf) & 3) * 1024; \
        Af[rf * 2]     = *(const bf16x8*)&LA[rb + lo0]; \
        Af[rf * 2 + 1] = *(const bf16x8*)&LA[rb + lo1]; } }
#define RD_B(dst, cfb) { _Pragma("unroll") for (int cf = 0; cf < 2; ++cf) { \
        const int cb = cbase + ((cfb) + cf) * 1024; \
        dst[cf * 2]     = *(const bf16x8*)&LB[cb + lo0]; \
        dst[cf * 2 + 1] = *(const bf16x8*)&LB[cb + lo1]; } }
#define MM16(rfb, Bv, cfb) { _Pragma("unroll") for (int kk = 0; kk < 2; ++kk) \
        _Pragma("unroll") for (int rf = 0; rf < 4; ++rf) \
        _Pragma("unroll") for (int cf = 0; cf < 2; ++cf) \
            acc[(rfb) + rf][(cfb) + cf] = __builtin_amdgcn_mfma_f32_16x16x32_bf16( \
                Af[rf * 2 + kk], Bv[cf * 2 + kk], acc[(rfb) + rf][(cfb) + cf], 0, 0, 0); }
#define BAR __builtin_amdgcn_s_barrier()
#define PRI(x) __builtin_amdgcn_s_setprio(x)
#define VMW(n) { asm volatile("s_waitcnt vmcnt(" #n ")" ::: "memory"); \
                 __builtin_amdgcn_sched_barrier(0); }

    // ---- prologue: b0 full (B then A), b1-B-h0; leave last 2 outstanding ----
    stB(0, 0, 0); stB(0, 1, 0);
    stA(0, 0, 0); stA(0, 1, 0);
    stB(1, 0, 1);
    VMW(2);
    BAR;

    for (int i = 0; i < NSTEP / 2; ++i) {
        const int s = 2 * i;
        const bool g2 = (s + 2 < NSTEP);
        const bool g3 = (s + 3 < NSTEP);
        // ======== K-step s (buf 0) ========
        {
            const short* LA = &L[0][0][wm][0];
            const short* LB = &L[0][1][wnh][0];
            // p1
            RD_A(0) RD_B(Bq01, 0)
            stB(1, 1, s + 1);
            BAR; PRI(1); MM16(0, Bq01, 0) PRI(0);
            // p2
            RD_B(Bq23, 2)
            stA(1, 0, s + 1);
            BAR; PRI(1); MM16(0, Bq23, 2) PRI(0);
            // p3
            RD_A(4)
            stA(1, 1, s + 1);
            BAR; PRI(1); MM16(4, Bq01, 0) PRI(0);
            // p4
            if (g2) stB(0, 0, s + 2);
            BAR; PRI(1); MM16(4, Bq23, 2) PRI(0);
            if (g2) { VMW(2); } else { VMW(0); }
            BAR;
        }
        // ======== K-step s+1 (buf 1) ========
        {
            const short* LA = &L[1][0][wm][0];
            const short* LB = &L[1][1][wnh][0];
            // p5
            RD_A(0) RD_B(Bq01, 0)
            if (g2) stB(0, 1, s + 2);
            BAR; PRI(1); MM16(0, Bq01, 0) PRI(0);
            // p6
            RD_B(Bq23, 2)
            if (g2) stA(0, 0, s + 2);
            BAR; PRI(1); MM16(0, Bq23, 2) PRI(0);
            // p7
            RD_A(4)
            if (g2) stA(0, 1, s + 2);
            BAR; PRI(1); MM16(4, Bq01, 0) PRI(0);
            // p8
            if (g3) stB(1, 0, s + 3);
            BAR; PRI(1); MM16(4, Bq23, 2) PRI(0);
            if (i < NSTEP / 2 - 1) {
                if (g3) { VMW(2); } else { VMW(0); }
                BAR;
            }
        }
    }
#undef RD_A
#undef RD_B
#undef MM16
#undef BAR
#undef PRI
#undef VMW

    // ---- epilogue: C/D layout col=lane&15, row=(lane>>4)*4+reg ----
    int col0 = n0 + wn * 64 + (lane & 15);
    int row0 = m0 + wm * 128 + (lane >> 4) * 4;
#pragma unroll
    for (int f = 0; f < 8; ++f)
#pragma unroll
        for (int j = 0; j < 4; ++j) {
            f32x4 v = acc[f][j];
            int r = row0 + f * 16;
            int c = col0 + j * 16;
#pragma unroll
            for (int q = 0; q < 4; ++q)
                out[(size_t)(r + q) * N_TOTAL + c] = v[q];
        }
}

// ---------------------------------------------------------------------------
// Tier B: m97-structure GEMM, A reg-staged from f32 X (round-5 verified).
// ---------------------------------------------------------------------------
__global__ __launch_bounds__(256) void k_gemm2b(const float* __restrict__ X,
                                                const __hip_bfloat16* __restrict__ Wb,
                                                float* __restrict__ out) {
    __shared__ __align__(16) short As[128 * 32];
    __shared__ __align__(16) short Bs[128 * 32];
    int bid = blockIdx.x;
    int swz = (bid & 7) * 512 + (bid >> 3);
    int bn = swz & 31, bm = swz >> 5;
    int m0 = bm * 128, n0 = bn * 128;
    int t = threadIdx.x, lane = t & 63, wv = t >> 6;
    int wr = wv >> 1, wc = wv & 1;
    f32x4 acc[4][4];
#pragma unroll
    for (int i = 0; i < 4; ++i)
#pragma unroll
        for (int j = 0; j < 4; ++j) acc[i][j] = (f32x4)(0.0f);
    int arow = t >> 2, acol = (t & 3) * 8;
    const float* Agf0 = X + (size_t)(m0 + arow) * K_TOTAL + acol;
    const float* Agf1 = Agf0 + (size_t)64 * K_TOTAL;
    const __hip_bfloat16* Bg0 = Wb + (size_t)(n0 + arow) * K_TOTAL + acol;
    const __hip_bfloat16* Bg1 = Bg0 + (size_t)64 * K_TOTAL;
    float4 xa0 = *(const float4*)(Agf0), xa1 = *(const float4*)(Agf0 + 4);
    float4 xb0 = *(const float4*)(Agf1), xb1 = *(const float4*)(Agf1 + 4);
    for (int kt = 0; kt < NT32; ++kt) {
        if (kt) __syncthreads();
        __hip_bfloat162 oa[4] = {
            __float22bfloat162_rn(make_float2(xa0.x, xa0.y)),
            __float22bfloat162_rn(make_float2(xa0.z, xa0.w)),
            __float22bfloat162_rn(make_float2(xa1.x, xa1.y)),
            __float22bfloat162_rn(make_float2(xa1.z, xa1.w))};
        __hip_bfloat162 ob[4] = {
            __float22bfloat162_rn(make_float2(xb0.x, xb0.y)),
            __float22bfloat162_rn(make_float2(xb0.z, xb0.w)),
            __float22bfloat162_rn(make_float2(xb1.x, xb1.y)),
            __float22bfloat162_rn(make_float2(xb1.z, xb1.w))};
        *(int4*)&As[t * 8] = *(int4*)&oa[0];
        *(int4*)&As[2048 + t * 8] = *(int4*)&ob[0];
        gload_lds16(Bg0 + kt * 32, &Bs[t * 8]);
        gload_lds16(Bg1 + kt * 32, &Bs[2048 + t * 8]);
        __syncthreads();
        if (kt < NT32 - 1) {
            int ko = (kt + 1) * 32;
            xa0 = *(const float4*)(Agf0 + ko);
            xa1 = *(const float4*)(Agf0 + ko + 4);
            xb0 = *(const float4*)(Agf1 + ko);
            xb1 = *(const float4*)(Agf1 + ko + 4);
        }
        bf16x8 a[4], b[4];
        int ro = (lane & 15) * 32 + (lane >> 4) * 8;
#pragma unroll
        for (int i = 0; i < 4; ++i)
            a[i] = *(const bf16x8*)&As[(wr * 64 + i * 16) * 32 + ro];
#pragma unroll
        for (int j = 0; j < 4; ++j)
            b[j] = *(const bf16x8*)&Bs[(wc * 64 + j * 16) * 32 + ro];
#pragma unroll
        for (int i = 0; i < 4; ++i)
#pragma unroll
            for (int j = 0; j < 4; ++j)
                acc[i][j] = __builtin_amdgcn_mfma_f32_16x16x32_bf16(a[i], b[j], acc[i][j], 0, 0, 0);
    }
    int col0 = n0 + wc * 64 + (lane & 15);
    int row0 = m0 + wr * 64 + (lane >> 4) * 4;
#pragma unroll
    for (int i = 0; i < 4; ++i)
#pragma unroll
        for (int j = 0; j < 4; ++j) {
            f32x4 v = acc[i][j];
            int r = row0 + i * 16, c = col0 + j * 16;
#pragma unroll
            for (int q = 0; q < 4; ++q)
                out[(size_t)(r + q) * N_TOTAL + c] = v[q];
        }
}

extern "C" void kernel_launch(void* const* d_in, const int* in_sizes, int n_in,
                              void* d_out, int out_size, void* d_ws, size_t ws_size,
                              hipStream_t stream) {
    const float* X = (const float*)d_in[0];
    const int* PW = (const int*)d_in[1];
    const float* SC = (const float*)d_in[2];
    float* OUT = (float*)d_out;

    const size_t needW = (size_t)N_TOTAL * K_TOTAL * 2;            // 33.5 MB
    const size_t needX = needW + (size_t)M_TOTAL * K_TOTAL * 2;    // +134 MB

    if (ws_size >= needX) {
        __hip_bfloat16* Wb = (__hip_bfloat16*)d_ws;
        __hip_bfloat16* Xb = (__hip_bfloat16*)((char*)d_ws + needW);
        k_convX<<<dim3(32768), dim3(256), 0, stream>>>(X, Xb);
        k_dequant<<<dim3(4096), dim3(256), 0, stream>>>(PW, SC, Wb);
        k_gemm8<<<dim3((M_TOTAL / 256) * (N_TOTAL / 256)), dim3(512), 0, stream>>>(Xb, Wb, OUT);
    } else if (ws_size >= needW) {
        __hip_bfloat16* Wb = (__hip_bfloat16*)d_ws;
        k_dequant<<<dim3(4096), dim3(256), 0, stream>>>(PW, SC, Wb);
        k_gemm2b<<<dim3((M_TOTAL / 128) * (N_TOTAL / 128)), dim3(256), 0, stream>>>(X, Wb, OUT);
    }
}